// Round 10
// baseline (181.396 us; speedup 1.0000x reference)
//
#include <hip/hip_runtime.h>
#include <hip/hip_bf16.h>

// h_out[v] = sum over edges (u->v) of features[u]
// Round-9b: round-7 chassis (single block per bucket, exclusive stores, no
// memset) + NONTEMPORAL gathers in k6 (bdata + fp): both streams have zero
// L1 reuse, so bypass L1 allocation on the miss path. A/B experiment for
// the ~4.3 cyc/scattered-request floor: L1-fill overhead vs TA processing.
// (9a failed to compile: __builtin_nontemporal_load rejects HIP uint4 class;
//  fp is gathered via an ext_vector_type(4) alias instead.)
// k25/k7/k1 unchanged from round 7.

#define NN     100000
#define FD     5
#define NOUTT  (NN * FD)      // 500000
#define NPS    32             // nodes per bucket
#define NPS_SH 5
#define NB     3125           // 100000 / 32 exactly
#define NBP1   3126           // pscan row length (sentinel row[NB] = chunk)
#define NSB    512            // chunks (chunk = 12500 edges)
#define BLK    256
#define BLK25  1024           // k25 block
#define K25VPT 4              // 4*1024 = 4096 >= 3125
#define CAPE   12800          // max chunk held in LDS seg (50KB + h 12.5KB)
#define NXCD   8

typedef int      vint4  __attribute__((ext_vector_type(4)));
typedef unsigned vuint4 __attribute__((ext_vector_type(4)));  // NT-load-safe

__device__ inline unsigned bf16rtn(float x) {          // fp32 -> bf16 (RTN)
    unsigned u = __float_as_uint(x);
    u += 0x7fffu + ((u >> 16) & 1u);
    return u >> 16;
}
__device__ inline float lo16(unsigned v) { return __uint_as_float(v << 16); }
__device__ inline float hi16(unsigned v) { return __uint_as_float(v & 0xffff0000u); }

// XCD-contiguous chunk assignment (512 = 8*64 exact).
__device__ inline int chunk_of_block(int bid) {
    return (bid & (NXCD - 1)) * (NSB / NXCD) + (bid >> 3);
}
// Bijective consecutive-buckets -> same-XCD mapping for k6 (3125 = 8*390+5).
__device__ inline int bucket_of_block(int bid) {
    int xcd = bid & 7, idx = bid >> 3;
    int q = NB >> 3, r = NB & 7;                       // 390, 5
    return (xcd < r) ? xcd * (q + 1) + idx
                     : r * (q + 1) + (xcd - r) * q + idx;
}

// ---------- K25: fully in-LDS per-chunk counting sort (unchanged) -----------
__global__ __launch_bounds__(BLK25) void k25_sortchunk(
        const int* __restrict__ src, const int* __restrict__ dst,
        unsigned short* __restrict__ bh, int* __restrict__ bdata, int chunk) {
    __shared__ int h[NB];         // counts -> then LOCAL exclusive bases
    __shared__ int seg[CAPE];     // chunk sorted by bucket (50 KB)
    __shared__ int wv[16];
    int t = threadIdx.x;
    for (int b = t; b < NB; b += BLK25) h[b] = 0;
    __syncthreads();
    int cblk = chunk_of_block(blockIdx.x);
    long long e0 = (long long)cblk * chunk;
    const vint4* d4 = (const vint4*)(dst + e0);
    const vint4* s4 = (const vint4*)(src + e0);
    int n4 = chunk >> 2;          // <= 3200 (gate) -> <= 4 iters/thread

    int bk0[4], bk1[4], bk2[4], bk3[4];   // buckets, iter 0..3
    int wd0[4], wd1[4], wd2[4], wd3[4];   // packed words
    int rk0[4], rk1[4], rk2[4], rk3[4];   // ranks
    bool a0v, a1v, a2v, a3v;
#define LOADIT(IT, BK, WD)                                             \
    {                                                                  \
        int i = t + IT * BLK25;                                        \
        if (i < n4) {                                                  \
            vint4 d = __builtin_nontemporal_load(&d4[i]);              \
            vint4 s = __builtin_nontemporal_load(&s4[i]);              \
            BK[0] = d[0] >> NPS_SH; WD[0] = (s[0] << NPS_SH) | (d[0] & (NPS - 1)); \
            BK[1] = d[1] >> NPS_SH; WD[1] = (s[1] << NPS_SH) | (d[1] & (NPS - 1)); \
            BK[2] = d[2] >> NPS_SH; WD[2] = (s[2] << NPS_SH) | (d[2] & (NPS - 1)); \
            BK[3] = d[3] >> NPS_SH; WD[3] = (s[3] << NPS_SH) | (d[3] & (NPS - 1)); \
        }                                                              \
    }
    a0v = (t < n4);               LOADIT(0, bk0, wd0)
    a1v = (t + BLK25 < n4);       LOADIT(1, bk1, wd1)
    a2v = (t + 2 * BLK25 < n4);   LOADIT(2, bk2, wd2)
    a3v = (t + 3 * BLK25 < n4);   LOADIT(3, bk3, wd3)
#undef LOADIT
#define RANKIT(AV, BK, RK)                                             \
    if (AV) {                                                          \
        RK[0] = atomicAdd(&h[BK[0]], 1);                               \
        RK[1] = atomicAdd(&h[BK[1]], 1);                               \
        RK[2] = atomicAdd(&h[BK[2]], 1);                               \
        RK[3] = atomicAdd(&h[BK[3]], 1);                               \
    }
    RANKIT(a0v, bk0, rk0)
    RANKIT(a1v, bk1, rk1)
    RANKIT(a2v, bk2, rk2)
    RANKIT(a3v, bk3, rk3)
#undef RANKIT
    __syncthreads();

    int v[K25VPT], sum = 0;
#pragma unroll
    for (int k = 0; k < K25VPT; ++k) {
        int j = K25VPT * t + k;
        v[k] = (j < NB) ? h[j] : 0;
        sum += v[k];
    }
    int lane = t & 63, wid = t >> 6;
    int sc = sum;
#pragma unroll
    for (int off = 1; off < 64; off <<= 1) {
        int u = __shfl_up(sc, off, 64);
        if (lane >= off) sc += u;
    }
    if (lane == 63) wv[wid] = sc;
    __syncthreads();
    int woff = 0;
#pragma unroll
    for (int w2 = 0; w2 < 16; ++w2) woff += (w2 < wid) ? wv[w2] : 0;
    int run = woff + sc - sum;    // LOCAL exclusive prefix for j = 4t
    unsigned short* row = bh + (size_t)cblk * NBP1;
#pragma unroll
    for (int k = 0; k < K25VPT; ++k) {
        int j = K25VPT * t + k;
        if (j < NB) { row[j] = (unsigned short)run; h[j] = run; }
        run += v[k];
    }
    if (t == 0) row[NB] = (unsigned short)chunk;
    __syncthreads();

#define SCAT(AV, BK, WD, RK)                                           \
    if (AV) {                                                          \
        seg[h[BK[0]] + RK[0]] = WD[0];                                 \
        seg[h[BK[1]] + RK[1]] = WD[1];                                 \
        seg[h[BK[2]] + RK[2]] = WD[2];                                 \
        seg[h[BK[3]] + RK[3]] = WD[3];                                 \
    }
    SCAT(a0v, bk0, wd0, rk0)
    SCAT(a1v, bk1, wd1, rk1)
    SCAT(a2v, bk2, wd2, rk2)
    SCAT(a3v, bk3, wd3, rk3)
#undef SCAT
    __syncthreads();

    vint4* out4 = (vint4*)(bdata + (size_t)cblk * chunk);
    const vint4* s4l = (const vint4*)seg;
    for (int i = t; i < n4; i += BLK25) out4[i] = s4l[i];
}

// ---------- K7: transpose bh [chunk][bucket] -> bhT [bucket][chunk] --------
#define TD 64
__global__ __launch_bounds__(256) void k7_transpose(const unsigned short* __restrict__ bh,
                                                    unsigned short* __restrict__ bhT) {
    __shared__ unsigned short tile[TD][TD + 1];
    int jx = blockIdx.x * TD;      // bucket-dim tile origin
    int cy = blockIdx.y * TD;      // chunk-dim tile origin
    int tx = threadIdx.x & (TD - 1);
    int ty = threadIdx.x >> 6;     // 0..3
#pragma unroll
    for (int r = 0; r < 16; ++r) {
        int c = cy + ty + 4 * r;
        int j = jx + tx;
        tile[ty + 4 * r][tx] =
            (j < NBP1) ? bh[(size_t)c * NBP1 + j] : (unsigned short)0;
    }
    __syncthreads();
#pragma unroll
    for (int r = 0; r < 16; ++r) {
        int j = jx + ty + 4 * r;
        int c = cy + tx;
        if (j < NBP1) bhT[(size_t)j * NSB + c] = tile[tx][ty + 4 * r];
    }
}

// ---------- K1: bf16-pack rows 5 f32 -> 16 B --------------------------------
__global__ __launch_bounds__(BLK) void k1_pad(const float* __restrict__ f,
                                              vuint4* __restrict__ fp) {
    int i = blockIdx.x * BLK + threadIdx.x;
    if (i < NN) {
        const float* r = f + (long long)i * FD;
        unsigned w0 = bf16rtn(r[0]), w1 = bf16rtn(r[1]), w2 = bf16rtn(r[2]);
        unsigned w3 = bf16rtn(r[3]), w4 = bf16rtn(r[4]);
        vuint4 o;
        o[0] = w0 | (w1 << 16);
        o[1] = w2 | (w3 << 16);
        o[2] = w4;
        o[3] = 0u;
        fp[i] = o;
    }
}

// ---------- K6: one block per bucket — producer map + NONTEMPORAL gathers ---
#define CAP 3072              // window capacity (bucket mean 2048, max ~2.3K)
#define WPT (CAP / BLK)       // 12
__global__ __launch_bounds__(BLK) void k6_gather(const int* __restrict__ bdata,
                                                 const vuint4* __restrict__ fp,
                                                 const unsigned short* __restrict__ bhT,
                                                 float* __restrict__ out, int chunk) {
    __shared__ int mapseg[CAP];       // phase A: bdata-index map; phase B: seg
    __shared__ int hist[NPS];
    __shared__ int sbase[NPS];
    __shared__ int wsum[BLK / 64];
    int t = threadIdx.x;
    int b = bucket_of_block(blockIdx.x);

    // Phase 0: coalesced (start,len) for chunks 2t,2t+1 from bhT rows b,b+1.
    const unsigned* r0 = (const unsigned*)(bhT + (size_t)b * NSB);
    const unsigned* r1 = (const unsigned*)(bhT + (size_t)(b + 1) * NSB);
    unsigned s0 = r0[t], s1 = r1[t];
    int st0 = (int)(s0 & 0xffffu), st1 = (int)(s0 >> 16);
    int l0 = (int)(s1 & 0xffffu) - st0;
    int l1 = (int)(s1 >> 16) - st1;
    int pair = l0 + l1;
    // wave-inclusive scan of pair (shfl; no barriers)
    int lane = t & 63, wid = t >> 6;
    int sc = pair;
#pragma unroll
    for (int off = 1; off < 64; off <<= 1) {
        int u = __shfl_up(sc, off, 64);
        if (lane >= off) sc += u;
    }
    if (lane == 63) wsum[wid] = sc;
    __syncthreads();
    int w0s = wsum[0], w1s = wsum[1], w2s = wsum[2], w3s = wsum[3];
    int woff = (wid > 0 ? w0s : 0) + (wid > 1 ? w1s : 0) + (wid > 2 ? w2s : 0);
    int n = w0s + w1s + w2s + w3s;            // bucket total
    int cum0 = woff + sc - pair;              // global rank of chunk 2t start
    int cumm = cum0 + l0;                     // global rank of chunk 2t+1 start
    int g0 = 2 * t * chunk + st0;             // bdata index of sub-range 2t
    int g1 = (2 * t + 1) * chunk + st1;       // bdata index of sub-range 2t+1

    int grp = t >> 3;             // node 0..31 this 8-thread team owns
    int sub = t & 7;
    float a0 = 0.f, a1 = 0.f, a2 = 0.f, a3 = 0.f, a4 = 0.f;

    for (int ws = 0; ws < n; ws += CAP) {
        int we = ws + CAP; if (we > n) we = n;
        int m = we - ws;
        if (t < NPS) hist[t] = 0;
        // Producer map-build: this thread's sub-ranges -> bdata indices.
        {
            int lo = cum0 > ws ? cum0 : ws;
            int hi = (cum0 + l0) < we ? (cum0 + l0) : we;
            for (int p = lo; p < hi; ++p) mapseg[p - ws] = g0 + (p - cum0);
            lo = cumm > ws ? cumm : ws;
            hi = (cumm + l1) < we ? (cumm + l1) : we;
            for (int p = lo; p < hi; ++p) mapseg[p - ws] = g1 + (p - cumm);
        }
        __syncthreads();

        // Gather: 12 independent (LDS map read -> NT bdata load), full ILP.
        int w[WPT], rk[WPT];
#pragma unroll
        for (int k = 0; k < WPT; ++k) {
            int idx = t + k * BLK;
            w[k] = (idx < m) ? __builtin_nontemporal_load(&bdata[mapseg[idx]])
                             : -1;
        }
        // Rank pass (the ONLY atomic): w >= 0 always for real entries.
#pragma unroll
        for (int k = 0; k < WPT; ++k)
            rk[k] = (w[k] >= 0) ? atomicAdd(&hist[w[k] & (NPS - 1)], 1) : 0;
        __syncthreads();

        // Exclusive scan of 32 counts (wave 0, lanes 0..31).
        if (t < NPS) {
            int v = hist[t];
            int scn = v;
#pragma unroll
            for (int off = 1; off < NPS; off <<= 1) {
                int u = __shfl_up(scn, off, 64);
                if (t >= off) scn += u;
            }
            sbase[t] = scn - v;
        }
        __syncthreads();

        // Scatter u into node-sorted position (overwrites map; w[] in regs).
#pragma unroll
        for (int k = 0; k < WPT; ++k) {
            if (w[k] >= 0)
                mapseg[sbase[w[k] & (NPS - 1)] + rk[k]] = w[k] >> NPS_SH;
        }
        __syncthreads();

        // Accumulate: 8 threads per node, strided slice, registers only.
        // fp gathers NONTEMPORAL: random 16B over 1.6MB, zero L1 reuse.
        int sg0 = sbase[grp], cnt = hist[grp];
        int j = sub;
        for (; j + 24 < cnt; j += 32) {
            int u0 = mapseg[sg0 + j],      u1 = mapseg[sg0 + j + 8];
            int u2 = mapseg[sg0 + j + 16], u3 = mapseg[sg0 + j + 24];
            vuint4 q0 = __builtin_nontemporal_load(&fp[u0]);
            vuint4 q1 = __builtin_nontemporal_load(&fp[u1]);
            vuint4 q2 = __builtin_nontemporal_load(&fp[u2]);
            vuint4 q3 = __builtin_nontemporal_load(&fp[u3]);
            a0 += lo16(q0[0]); a1 += hi16(q0[0]); a2 += lo16(q0[1]); a3 += hi16(q0[1]); a4 += lo16(q0[2]);
            a0 += lo16(q1[0]); a1 += hi16(q1[0]); a2 += lo16(q1[1]); a3 += hi16(q1[1]); a4 += lo16(q1[2]);
            a0 += lo16(q2[0]); a1 += hi16(q2[0]); a2 += lo16(q2[1]); a3 += hi16(q2[1]); a4 += lo16(q2[2]);
            a0 += lo16(q3[0]); a1 += hi16(q3[0]); a2 += lo16(q3[1]); a3 += hi16(q3[1]); a4 += lo16(q3[2]);
        }
        for (; j < cnt; j += 8) {
            int u = mapseg[sg0 + j];
            vuint4 q = __builtin_nontemporal_load(&fp[u]);
            a0 += lo16(q[0]); a1 += hi16(q[0]); a2 += lo16(q[1]); a3 += hi16(q[1]); a4 += lo16(q[2]);
        }
        __syncthreads();   // LDS reused next window
    }

    // Reduce the 8 partials per node within the 8-lane cluster.
    a0 += __shfl_down(a0, 4, 8); a0 += __shfl_down(a0, 2, 8); a0 += __shfl_down(a0, 1, 8);
    a1 += __shfl_down(a1, 4, 8); a1 += __shfl_down(a1, 2, 8); a1 += __shfl_down(a1, 1, 8);
    a2 += __shfl_down(a2, 4, 8); a2 += __shfl_down(a2, 2, 8); a2 += __shfl_down(a2, 1, 8);
    a3 += __shfl_down(a3, 4, 8); a3 += __shfl_down(a3, 2, 8); a3 += __shfl_down(a3, 1, 8);
    a4 += __shfl_down(a4, 4, 8); a4 += __shfl_down(a4, 2, 8); a4 += __shfl_down(a4, 1, 8);
    if (sub == 0) {
        // Exclusive owner; NB*NPS*FD == NOUTT exactly.
        float* o = out + (size_t)b * (NPS * FD) + grp * FD;
        o[0] = a0; o[1] = a1; o[2] = a2; o[3] = a3; o[4] = a4;
    }
}

// ---------- Fallback: direct global atomics ---------------------------------
__global__ void scatter_add_fallback(const float* __restrict__ features,
                                     const int* __restrict__ src,
                                     const int* __restrict__ dst,
                                     float* __restrict__ out, int n_edges) {
    int idx = blockIdx.x * blockDim.x + threadIdx.x;
    int stride = gridDim.x * blockDim.x;
    for (int e = idx; e < n_edges; e += stride) {
        int u = src[e], v = dst[e];
        const float* f = features + (long long)u * FD;
        float* o = out + (long long)v * FD;
#pragma unroll
        for (int k = 0; k < FD; ++k) atomicAdd(&o[k], f[k]);
    }
}

extern "C" void kernel_launch(void* const* d_in, const int* in_sizes, int n_in,
                              void* d_out, int out_size, void* d_ws, size_t ws_size,
                              hipStream_t stream) {
    const float* features = (const float*)d_in[0];
    const int*   src      = (const int*)d_in[1];
    const int*   dst      = (const int*)d_in[2];
    float* out = (float*)d_out;
    int n_edges = in_sizes[1];
    int chunk = n_edges / NSB;

    // ws carve: bdata | bh | bhT. fpad OVERLAPS bh (bh dead after k7; k1
    // runs after k7).
    size_t o_bd = 0;                                        // bdata: E*4
    size_t o_bh = o_bd + (size_t)n_edges * 4;               // bh:  NSB*NBP1*2
    size_t sz_bh = (size_t)NSB * NBP1 * 2;                  // 3.2MB
    size_t o_bt = o_bh + ((sz_bh + 15) & ~(size_t)15);      // bhT: NBP1*NSB*2
    size_t o_fp = o_bh;                                     // fpad: NN*16 (1.6MB <= sz_bh)
    size_t need = o_bt + ((sz_bh + 15) & ~(size_t)15);

    bool fast = (out_size == NOUTT) && (in_sizes[0] == NOUTT) &&
                (n_edges % (NSB * 4) == 0) && (chunk <= CAPE) &&
                (need <= ws_size);

    if (fast) {
        char* w = (char*)d_ws;
        int*            bdata = (int*)(w + o_bd);
        unsigned short* bh    = (unsigned short*)(w + o_bh);
        unsigned short* bhT   = (unsigned short*)(w + o_bt);
        vuint4*         fpad  = (vuint4*)(w + o_fp);
        dim3 g7((NBP1 + TD - 1) / TD, NSB / TD);
        k25_sortchunk<<<NSB, BLK25, 0, stream>>>(src, dst, bh, bdata, chunk);
        k7_transpose <<<g7, 256, 0, stream>>>(bh, bhT);
        k1_pad       <<<(NN + BLK - 1) / BLK, BLK, 0, stream>>>(features, fpad);
        k6_gather    <<<NB, BLK, 0, stream>>>(bdata, fpad, bhT, out, chunk);
    } else {
        (void)hipMemsetAsync(d_out, 0, (size_t)out_size * sizeof(float), stream);
        int grid = (n_edges + BLK - 1) / BLK;
        if (grid > 65535) grid = 65535;
        scatter_add_fallback<<<grid, BLK, 0, stream>>>(features, src, dst, out, n_edges);
    }
}

// Round 11
// 151.067 us; speedup vs baseline: 1.2008x; 1.2008x over previous
//
#include <hip/hip_runtime.h>
#include <hip/hip_bf16.h>

// h_out[v] = sum over edges (u->v) of features[u]
// Round-11: REVERT to best-known config (round-7 structure). NT removed from
// k6's gathers — round-10 proved nt also early-evicts L2 on gfx950, turning
// the L2-resident fp table + bdata slice into HBM fetches (k6 45->70us,
// FETCH 2x). k6's 45us floor survived chain-removal (R7), 2x TLP (R8), and
// L1 bypass (R10): per-CU miss-handling throughput on the inherent
// 1-random-16B-gather-per-edge. k25/k7/k1 unchanged.

#define NN     100000
#define FD     5
#define NOUTT  (NN * FD)      // 500000
#define NPS    32             // nodes per bucket
#define NPS_SH 5
#define NB     3125           // 100000 / 32 exactly
#define NBP1   3126           // pscan row length (sentinel row[NB] = chunk)
#define NSB    512            // chunks (chunk = 12500 edges)
#define BLK    256
#define BLK25  1024           // k25 block
#define K25VPT 4              // 4*1024 = 4096 >= 3125
#define CAPE   12800          // max chunk held in LDS seg (50KB + h 12.5KB)
#define NXCD   8

typedef int      vint4  __attribute__((ext_vector_type(4)));
typedef unsigned vuint4 __attribute__((ext_vector_type(4)));

__device__ inline unsigned bf16rtn(float x) {          // fp32 -> bf16 (RTN)
    unsigned u = __float_as_uint(x);
    u += 0x7fffu + ((u >> 16) & 1u);
    return u >> 16;
}
__device__ inline float lo16(unsigned v) { return __uint_as_float(v << 16); }
__device__ inline float hi16(unsigned v) { return __uint_as_float(v & 0xffff0000u); }

// XCD-contiguous chunk assignment (512 = 8*64 exact).
__device__ inline int chunk_of_block(int bid) {
    return (bid & (NXCD - 1)) * (NSB / NXCD) + (bid >> 3);
}
// Bijective consecutive-buckets -> same-XCD mapping for k6 (3125 = 8*390+5).
__device__ inline int bucket_of_block(int bid) {
    int xcd = bid & 7, idx = bid >> 3;
    int q = NB >> 3, r = NB & 7;                       // 390, 5
    return (xcd < r) ? xcd * (q + 1) + idx
                     : r * (q + 1) + (xcd - r) * q + idx;
}

// ---------- K25: fully in-LDS per-chunk counting sort (unchanged) -----------
__global__ __launch_bounds__(BLK25) void k25_sortchunk(
        const int* __restrict__ src, const int* __restrict__ dst,
        unsigned short* __restrict__ bh, int* __restrict__ bdata, int chunk) {
    __shared__ int h[NB];         // counts -> then LOCAL exclusive bases
    __shared__ int seg[CAPE];     // chunk sorted by bucket (50 KB)
    __shared__ int wv[16];
    int t = threadIdx.x;
    for (int b = t; b < NB; b += BLK25) h[b] = 0;
    __syncthreads();
    int cblk = chunk_of_block(blockIdx.x);
    long long e0 = (long long)cblk * chunk;
    const vint4* d4 = (const vint4*)(dst + e0);
    const vint4* s4 = (const vint4*)(src + e0);
    int n4 = chunk >> 2;          // <= 3200 (gate) -> <= 4 iters/thread

    int bk0[4], bk1[4], bk2[4], bk3[4];   // buckets, iter 0..3
    int wd0[4], wd1[4], wd2[4], wd3[4];   // packed words
    int rk0[4], rk1[4], rk2[4], rk3[4];   // ranks
    bool a0v, a1v, a2v, a3v;
#define LOADIT(IT, BK, WD)                                             \
    {                                                                  \
        int i = t + IT * BLK25;                                        \
        if (i < n4) {                                                  \
            vint4 d = __builtin_nontemporal_load(&d4[i]);              \
            vint4 s = __builtin_nontemporal_load(&s4[i]);              \
            BK[0] = d[0] >> NPS_SH; WD[0] = (s[0] << NPS_SH) | (d[0] & (NPS - 1)); \
            BK[1] = d[1] >> NPS_SH; WD[1] = (s[1] << NPS_SH) | (d[1] & (NPS - 1)); \
            BK[2] = d[2] >> NPS_SH; WD[2] = (s[2] << NPS_SH) | (d[2] & (NPS - 1)); \
            BK[3] = d[3] >> NPS_SH; WD[3] = (s[3] << NPS_SH) | (d[3] & (NPS - 1)); \
        }                                                              \
    }
    a0v = (t < n4);               LOADIT(0, bk0, wd0)
    a1v = (t + BLK25 < n4);       LOADIT(1, bk1, wd1)
    a2v = (t + 2 * BLK25 < n4);   LOADIT(2, bk2, wd2)
    a3v = (t + 3 * BLK25 < n4);   LOADIT(3, bk3, wd3)
#undef LOADIT
#define RANKIT(AV, BK, RK)                                             \
    if (AV) {                                                          \
        RK[0] = atomicAdd(&h[BK[0]], 1);                               \
        RK[1] = atomicAdd(&h[BK[1]], 1);                               \
        RK[2] = atomicAdd(&h[BK[2]], 1);                               \
        RK[3] = atomicAdd(&h[BK[3]], 1);                               \
    }
    RANKIT(a0v, bk0, rk0)
    RANKIT(a1v, bk1, rk1)
    RANKIT(a2v, bk2, rk2)
    RANKIT(a3v, bk3, rk3)
#undef RANKIT
    __syncthreads();

    int v[K25VPT], sum = 0;
#pragma unroll
    for (int k = 0; k < K25VPT; ++k) {
        int j = K25VPT * t + k;
        v[k] = (j < NB) ? h[j] : 0;
        sum += v[k];
    }
    int lane = t & 63, wid = t >> 6;
    int sc = sum;
#pragma unroll
    for (int off = 1; off < 64; off <<= 1) {
        int u = __shfl_up(sc, off, 64);
        if (lane >= off) sc += u;
    }
    if (lane == 63) wv[wid] = sc;
    __syncthreads();
    int woff = 0;
#pragma unroll
    for (int w2 = 0; w2 < 16; ++w2) woff += (w2 < wid) ? wv[w2] : 0;
    int run = woff + sc - sum;    // LOCAL exclusive prefix for j = 4t
    unsigned short* row = bh + (size_t)cblk * NBP1;
#pragma unroll
    for (int k = 0; k < K25VPT; ++k) {
        int j = K25VPT * t + k;
        if (j < NB) { row[j] = (unsigned short)run; h[j] = run; }
        run += v[k];
    }
    if (t == 0) row[NB] = (unsigned short)chunk;
    __syncthreads();

#define SCAT(AV, BK, WD, RK)                                           \
    if (AV) {                                                          \
        seg[h[BK[0]] + RK[0]] = WD[0];                                 \
        seg[h[BK[1]] + RK[1]] = WD[1];                                 \
        seg[h[BK[2]] + RK[2]] = WD[2];                                 \
        seg[h[BK[3]] + RK[3]] = WD[3];                                 \
    }
    SCAT(a0v, bk0, wd0, rk0)
    SCAT(a1v, bk1, wd1, rk1)
    SCAT(a2v, bk2, wd2, rk2)
    SCAT(a3v, bk3, wd3, rk3)
#undef SCAT
    __syncthreads();

    vint4* out4 = (vint4*)(bdata + (size_t)cblk * chunk);
    const vint4* s4l = (const vint4*)seg;
    for (int i = t; i < n4; i += BLK25) out4[i] = s4l[i];
}

// ---------- K7: transpose bh [chunk][bucket] -> bhT [bucket][chunk] --------
#define TD 64
__global__ __launch_bounds__(256) void k7_transpose(const unsigned short* __restrict__ bh,
                                                    unsigned short* __restrict__ bhT) {
    __shared__ unsigned short tile[TD][TD + 1];
    int jx = blockIdx.x * TD;      // bucket-dim tile origin
    int cy = blockIdx.y * TD;      // chunk-dim tile origin
    int tx = threadIdx.x & (TD - 1);
    int ty = threadIdx.x >> 6;     // 0..3
#pragma unroll
    for (int r = 0; r < 16; ++r) {
        int c = cy + ty + 4 * r;
        int j = jx + tx;
        tile[ty + 4 * r][tx] =
            (j < NBP1) ? bh[(size_t)c * NBP1 + j] : (unsigned short)0;
    }
    __syncthreads();
#pragma unroll
    for (int r = 0; r < 16; ++r) {
        int j = jx + ty + 4 * r;
        int c = cy + tx;
        if (j < NBP1) bhT[(size_t)j * NSB + c] = tile[tx][ty + 4 * r];
    }
}

// ---------- K1: bf16-pack rows 5 f32 -> 16 B --------------------------------
__global__ __launch_bounds__(BLK) void k1_pad(const float* __restrict__ f,
                                              vuint4* __restrict__ fp) {
    int i = blockIdx.x * BLK + threadIdx.x;
    if (i < NN) {
        const float* r = f + (long long)i * FD;
        unsigned w0 = bf16rtn(r[0]), w1 = bf16rtn(r[1]), w2 = bf16rtn(r[2]);
        unsigned w3 = bf16rtn(r[3]), w4 = bf16rtn(r[4]);
        vuint4 o;
        o[0] = w0 | (w1 << 16);
        o[1] = w2 | (w3 << 16);
        o[2] = w4;
        o[3] = 0u;
        fp[i] = o;
    }
}

// ---------- K6: one block per bucket — producer map, PLAIN (L2-backed) ------
#define CAP 3072              // window capacity (bucket mean 2048, max ~2.3K)
#define WPT (CAP / BLK)       // 12
__global__ __launch_bounds__(BLK) void k6_gather(const int* __restrict__ bdata,
                                                 const vuint4* __restrict__ fp,
                                                 const unsigned short* __restrict__ bhT,
                                                 float* __restrict__ out, int chunk) {
    __shared__ int mapseg[CAP];       // phase A: bdata-index map; phase B: seg
    __shared__ int hist[NPS];
    __shared__ int sbase[NPS];
    __shared__ int wsum[BLK / 64];
    int t = threadIdx.x;
    int b = bucket_of_block(blockIdx.x);

    // Phase 0: coalesced (start,len) for chunks 2t,2t+1 from bhT rows b,b+1.
    const unsigned* r0 = (const unsigned*)(bhT + (size_t)b * NSB);
    const unsigned* r1 = (const unsigned*)(bhT + (size_t)(b + 1) * NSB);
    unsigned s0 = r0[t], s1 = r1[t];
    int st0 = (int)(s0 & 0xffffu), st1 = (int)(s0 >> 16);
    int l0 = (int)(s1 & 0xffffu) - st0;
    int l1 = (int)(s1 >> 16) - st1;
    int pair = l0 + l1;
    // wave-inclusive scan of pair (shfl; no barriers)
    int lane = t & 63, wid = t >> 6;
    int sc = pair;
#pragma unroll
    for (int off = 1; off < 64; off <<= 1) {
        int u = __shfl_up(sc, off, 64);
        if (lane >= off) sc += u;
    }
    if (lane == 63) wsum[wid] = sc;
    __syncthreads();
    int w0s = wsum[0], w1s = wsum[1], w2s = wsum[2], w3s = wsum[3];
    int woff = (wid > 0 ? w0s : 0) + (wid > 1 ? w1s : 0) + (wid > 2 ? w2s : 0);
    int n = w0s + w1s + w2s + w3s;            // bucket total
    int cum0 = woff + sc - pair;              // global rank of chunk 2t start
    int cumm = cum0 + l0;                     // global rank of chunk 2t+1 start
    int g0 = 2 * t * chunk + st0;             // bdata index of sub-range 2t
    int g1 = (2 * t + 1) * chunk + st1;       // bdata index of sub-range 2t+1

    int grp = t >> 3;             // node 0..31 this 8-thread team owns
    int sub = t & 7;
    float a0 = 0.f, a1 = 0.f, a2 = 0.f, a3 = 0.f, a4 = 0.f;

    for (int ws = 0; ws < n; ws += CAP) {
        int we = ws + CAP; if (we > n) we = n;
        int m = we - ws;
        if (t < NPS) hist[t] = 0;
        // Producer map-build: this thread's sub-ranges -> bdata indices.
        {
            int lo = cum0 > ws ? cum0 : ws;
            int hi = (cum0 + l0) < we ? (cum0 + l0) : we;
            for (int p = lo; p < hi; ++p) mapseg[p - ws] = g0 + (p - cum0);
            lo = cumm > ws ? cumm : ws;
            hi = (cumm + l1) < we ? (cumm + l1) : we;
            for (int p = lo; p < hi; ++p) mapseg[p - ws] = g1 + (p - cumm);
        }
        __syncthreads();

        // Gather: 12 independent (LDS map read -> bdata load), full ILP.
        int w[WPT], rk[WPT];
#pragma unroll
        for (int k = 0; k < WPT; ++k) {
            int idx = t + k * BLK;
            w[k] = (idx < m) ? bdata[mapseg[idx]] : -1;
        }
        // Rank pass (the ONLY atomic): w >= 0 always for real entries.
#pragma unroll
        for (int k = 0; k < WPT; ++k)
            rk[k] = (w[k] >= 0) ? atomicAdd(&hist[w[k] & (NPS - 1)], 1) : 0;
        __syncthreads();

        // Exclusive scan of 32 counts (wave 0, lanes 0..31).
        if (t < NPS) {
            int v = hist[t];
            int scn = v;
#pragma unroll
            for (int off = 1; off < NPS; off <<= 1) {
                int u = __shfl_up(scn, off, 64);
                if (t >= off) scn += u;
            }
            sbase[t] = scn - v;
        }
        __syncthreads();

        // Scatter u into node-sorted position (overwrites map; w[] in regs).
#pragma unroll
        for (int k = 0; k < WPT; ++k) {
            if (w[k] >= 0)
                mapseg[sbase[w[k] & (NPS - 1)] + rk[k]] = w[k] >> NPS_SH;
        }
        __syncthreads();

        // Accumulate: 8 threads per node, strided slice, registers only.
        int sg0 = sbase[grp], cnt = hist[grp];
        int j = sub;
        for (; j + 24 < cnt; j += 32) {
            int u0 = mapseg[sg0 + j],      u1 = mapseg[sg0 + j + 8];
            int u2 = mapseg[sg0 + j + 16], u3 = mapseg[sg0 + j + 24];
            vuint4 q0 = fp[u0], q1 = fp[u1], q2 = fp[u2], q3 = fp[u3];
            a0 += lo16(q0[0]); a1 += hi16(q0[0]); a2 += lo16(q0[1]); a3 += hi16(q0[1]); a4 += lo16(q0[2]);
            a0 += lo16(q1[0]); a1 += hi16(q1[0]); a2 += lo16(q1[1]); a3 += hi16(q1[1]); a4 += lo16(q1[2]);
            a0 += lo16(q2[0]); a1 += hi16(q2[0]); a2 += lo16(q2[1]); a3 += hi16(q2[1]); a4 += lo16(q2[2]);
            a0 += lo16(q3[0]); a1 += hi16(q3[0]); a2 += lo16(q3[1]); a3 += hi16(q3[1]); a4 += lo16(q3[2]);
        }
        for (; j < cnt; j += 8) {
            int u = mapseg[sg0 + j];
            vuint4 q = fp[u];
            a0 += lo16(q[0]); a1 += hi16(q[0]); a2 += lo16(q[1]); a3 += hi16(q[1]); a4 += lo16(q[2]);
        }
        __syncthreads();   // LDS reused next window
    }

    // Reduce the 8 partials per node within the 8-lane cluster.
    a0 += __shfl_down(a0, 4, 8); a0 += __shfl_down(a0, 2, 8); a0 += __shfl_down(a0, 1, 8);
    a1 += __shfl_down(a1, 4, 8); a1 += __shfl_down(a1, 2, 8); a1 += __shfl_down(a1, 1, 8);
    a2 += __shfl_down(a2, 4, 8); a2 += __shfl_down(a2, 2, 8); a2 += __shfl_down(a2, 1, 8);
    a3 += __shfl_down(a3, 4, 8); a3 += __shfl_down(a3, 2, 8); a3 += __shfl_down(a3, 1, 8);
    a4 += __shfl_down(a4, 4, 8); a4 += __shfl_down(a4, 2, 8); a4 += __shfl_down(a4, 1, 8);
    if (sub == 0) {
        // Exclusive owner; NB*NPS*FD == NOUTT exactly.
        float* o = out + (size_t)b * (NPS * FD) + grp * FD;
        o[0] = a0; o[1] = a1; o[2] = a2; o[3] = a3; o[4] = a4;
    }
}

// ---------- Fallback: direct global atomics ---------------------------------
__global__ void scatter_add_fallback(const float* __restrict__ features,
                                     const int* __restrict__ src,
                                     const int* __restrict__ dst,
                                     float* __restrict__ out, int n_edges) {
    int idx = blockIdx.x * blockDim.x + threadIdx.x;
    int stride = gridDim.x * blockDim.x;
    for (int e = idx; e < n_edges; e += stride) {
        int u = src[e], v = dst[e];
        const float* f = features + (long long)u * FD;
        float* o = out + (long long)v * FD;
#pragma unroll
        for (int k = 0; k < FD; ++k) atomicAdd(&o[k], f[k]);
    }
}

extern "C" void kernel_launch(void* const* d_in, const int* in_sizes, int n_in,
                              void* d_out, int out_size, void* d_ws, size_t ws_size,
                              hipStream_t stream) {
    const float* features = (const float*)d_in[0];
    const int*   src      = (const int*)d_in[1];
    const int*   dst      = (const int*)d_in[2];
    float* out = (float*)d_out;
    int n_edges = in_sizes[1];
    int chunk = n_edges / NSB;

    // ws carve: bdata | bh | bhT. fpad OVERLAPS bh (bh dead after k7; k1
    // runs after k7).
    size_t o_bd = 0;                                        // bdata: E*4
    size_t o_bh = o_bd + (size_t)n_edges * 4;               // bh:  NSB*NBP1*2
    size_t sz_bh = (size_t)NSB * NBP1 * 2;                  // 3.2MB
    size_t o_bt = o_bh + ((sz_bh + 15) & ~(size_t)15);      // bhT: NBP1*NSB*2
    size_t o_fp = o_bh;                                     // fpad: NN*16 (1.6MB <= sz_bh)
    size_t need = o_bt + ((sz_bh + 15) & ~(size_t)15);

    bool fast = (out_size == NOUTT) && (in_sizes[0] == NOUTT) &&
                (n_edges % (NSB * 4) == 0) && (chunk <= CAPE) &&
                (need <= ws_size);

    if (fast) {
        char* w = (char*)d_ws;
        int*            bdata = (int*)(w + o_bd);
        unsigned short* bh    = (unsigned short*)(w + o_bh);
        unsigned short* bhT   = (unsigned short*)(w + o_bt);
        vuint4*         fpad  = (vuint4*)(w + o_fp);
        dim3 g7((NBP1 + TD - 1) / TD, NSB / TD);
        k25_sortchunk<<<NSB, BLK25, 0, stream>>>(src, dst, bh, bdata, chunk);
        k7_transpose <<<g7, 256, 0, stream>>>(bh, bhT);
        k1_pad       <<<(NN + BLK - 1) / BLK, BLK, 0, stream>>>(features, fpad);
        k6_gather    <<<NB, BLK, 0, stream>>>(bdata, fpad, bhT, out, chunk);
    } else {
        (void)hipMemsetAsync(d_out, 0, (size_t)out_size * sizeof(float), stream);
        int grid = (n_edges + BLK - 1) / BLK;
        if (grid > 65535) grid = 65535;
        scatter_add_fallback<<<grid, BLK, 0, stream>>>(features, src, dst, out, n_edges);
    }
}